// Round 1
// baseline (1943.186 us; speedup 1.0000x reference)
//
#include <hip/hip_runtime.h>
#include <math.h>

#define FDIM    512
#define HID     256
#define TILE_M  64
#define KT      16
#define PAD     257   // h-tile row stride: odd -> conflict-free scalar column reads
#define NTH     512
#define NEWTON_ITERS 14

// Fused: h1=relu(F@W1+b1); h2=relu(h1@W2+b2); o9=h2@W3+b3; mat=I+o9;
// X=rot@mat; out rot = polar(X) via det-scaled Newton (== U@Vh of SVD); logdet=0.
__global__ __launch_bounds__(NTH)
void cond9_fused(const float* __restrict__ rotp,
                 const float* __restrict__ feat,
                 const float* __restrict__ W1, const float* __restrict__ b1,
                 const float* __restrict__ W2, const float* __restrict__ b2,
                 const float* __restrict__ W3, const float* __restrict__ b3,
                 float* __restrict__ out, int n)
{
    __shared__ float As[KT * TILE_M];   // 4 KB; A-tile (transposed). Reused: out9[576]
    __shared__ float Bs[KT * HID];      // 16 KB; W-tile. Reused: W3 (2304) + b3 (at 2304..2312)
    __shared__ float h1[TILE_M * PAD];  // 65.8 KB
    __shared__ float h2[TILE_M * PAD];  // 65.8 KB

    const int tid  = threadIdx.x;
    const int tx   = tid & 31;   // col group: 8 cols each
    const int ty   = tid >> 5;   // row group: 4 rows each
    const int row0 = blockIdx.x * TILE_M;

    float acc[4][8];
    #pragma unroll
    for (int i = 0; i < 4; ++i)
        #pragma unroll
        for (int j = 0; j < 8; ++j) acc[i][j] = 0.0f;

    // ---------------- GEMM1: h1 = relu(feat @ W1 + b1) ----------------
    for (int k0 = 0; k0 < FDIM; k0 += KT) {
        __syncthreads();   // staging buffers free (prev compute done)
        if (tid < 256) {
            const int r  = tid >> 2;
            const int f4 = (tid & 3) << 2;
            int gr = row0 + r; if (gr >= n) gr = n - 1;   // defensive clamp
            const float4 v = *reinterpret_cast<const float4*>(
                feat + (size_t)gr * FDIM + k0 + f4);
            As[(f4 + 0) * TILE_M + r] = v.x;
            As[(f4 + 1) * TILE_M + r] = v.y;
            As[(f4 + 2) * TILE_M + r] = v.z;
            As[(f4 + 3) * TILE_M + r] = v.w;
        }
        #pragma unroll
        for (int i = 0; i < 2; ++i) {
            const int e  = tid + i * NTH;        // 0..1023
            const int kk = e >> 6;
            const int c4 = (e & 63) << 2;
            *reinterpret_cast<float4*>(Bs + kk * HID + c4) =
                *reinterpret_cast<const float4*>(W1 + (size_t)(k0 + kk) * HID + c4);
        }
        __syncthreads();
        #pragma unroll
        for (int kk = 0; kk < KT; ++kk) {
            const float4 a4  = *reinterpret_cast<const float4*>(As + kk * TILE_M + (ty << 2));
            const float4 blo = *reinterpret_cast<const float4*>(Bs + kk * HID + (tx << 3));
            const float4 bhi = *reinterpret_cast<const float4*>(Bs + kk * HID + (tx << 3) + 4);
            const float av[4] = {a4.x, a4.y, a4.z, a4.w};
            const float bv[8] = {blo.x, blo.y, blo.z, blo.w, bhi.x, bhi.y, bhi.z, bhi.w};
            #pragma unroll
            for (int i = 0; i < 4; ++i)
                #pragma unroll
                for (int j = 0; j < 8; ++j)
                    acc[i][j] = fmaf(av[i], bv[j], acc[i][j]);
        }
    }
    {   // epilogue 1: bias + relu -> h1 (LDS)
        float bv[8];
        #pragma unroll
        for (int j = 0; j < 8; ++j) bv[j] = b1[(tx << 3) + j];
        #pragma unroll
        for (int i = 0; i < 4; ++i)
            #pragma unroll
            for (int j = 0; j < 8; ++j)
                h1[((ty << 2) + i) * PAD + (tx << 3) + j] = fmaxf(acc[i][j] + bv[j], 0.0f);
    }
    #pragma unroll
    for (int i = 0; i < 4; ++i)
        #pragma unroll
        for (int j = 0; j < 8; ++j) acc[i][j] = 0.0f;

    // ---------------- GEMM2: h2 = relu(h1 @ W2 + b2) ----------------
    for (int k0 = 0; k0 < HID; k0 += KT) {
        __syncthreads();   // also guarantees h1 fully written before first compute
        #pragma unroll
        for (int i = 0; i < 2; ++i) {
            const int e  = tid + i * NTH;
            const int kk = e >> 6;
            const int c4 = (e & 63) << 2;
            *reinterpret_cast<float4*>(Bs + kk * HID + c4) =
                *reinterpret_cast<const float4*>(W2 + (size_t)(k0 + kk) * HID + c4);
        }
        __syncthreads();
        #pragma unroll
        for (int kk = 0; kk < KT; ++kk) {
            const int k = k0 + kk;
            float av[4];
            #pragma unroll
            for (int i = 0; i < 4; ++i) av[i] = h1[((ty << 2) + i) * PAD + k];
            const float4 blo = *reinterpret_cast<const float4*>(Bs + kk * HID + (tx << 3));
            const float4 bhi = *reinterpret_cast<const float4*>(Bs + kk * HID + (tx << 3) + 4);
            const float bv[8] = {blo.x, blo.y, blo.z, blo.w, bhi.x, bhi.y, bhi.z, bhi.w};
            #pragma unroll
            for (int i = 0; i < 4; ++i)
                #pragma unroll
                for (int j = 0; j < 8; ++j)
                    acc[i][j] = fmaf(av[i], bv[j], acc[i][j]);
        }
    }
    {   // epilogue 2: bias + relu -> h2 (LDS)
        float bv[8];
        #pragma unroll
        for (int j = 0; j < 8; ++j) bv[j] = b2[(tx << 3) + j];
        #pragma unroll
        for (int i = 0; i < 4; ++i)
            #pragma unroll
            for (int j = 0; j < 8; ++j)
                h2[((ty << 2) + i) * PAD + (tx << 3) + j] = fmaxf(acc[i][j] + bv[j], 0.0f);
    }
    __syncthreads();

    // ---------------- stage W3 (2304 floats) + b3 into Bs ----------------
    *reinterpret_cast<float4*>(Bs + tid * 4) =
        *reinterpret_cast<const float4*>(W3 + (size_t)tid * 4);
    if (tid < 64)
        *reinterpret_cast<float4*>(Bs + (NTH + tid) * 4) =
            *reinterpret_cast<const float4*>(W3 + (size_t)(NTH + tid) * 4);
    if (tid < 9) Bs[2304 + tid] = b3[tid];
    __syncthreads();

    // ---------------- GEMM3: out9[r][c] = h2[r,:] . W3[:,c] + b3[c] ----------------
    #pragma unroll
    for (int pass = 0; pass < 2; ++pass) {
        const int t = tid + pass * NTH;
        if (t < TILE_M * 9) {
            const int r = t / 9;
            const int c = t - r * 9;
            const float* hrow = h2 + r * PAD;
            float s0 = Bs[2304 + c], s1 = 0.0f, s2 = 0.0f, s3 = 0.0f;
            for (int k = 0; k < HID; k += 4) {
                s0 = fmaf(hrow[k + 0], Bs[(k + 0) * 9 + c], s0);
                s1 = fmaf(hrow[k + 1], Bs[(k + 1) * 9 + c], s1);
                s2 = fmaf(hrow[k + 2], Bs[(k + 2) * 9 + c], s2);
                s3 = fmaf(hrow[k + 3], Bs[(k + 3) * 9 + c], s3);
            }
            As[t] = (s0 + s1) + (s2 + s3);   // As reused as out9[64][9]
        }
    }
    __syncthreads();

    // ---------------- per-row 3x3: X = rot @ (I + out9); out = polar(X) ----------------
    if (tid < TILE_M) {
        const int r = row0 + tid;
        if (r < n) {
            float m[9];
            #pragma unroll
            for (int j = 0; j < 9; ++j) m[j] = As[tid * 9 + j];
            m[0] += 1.0f; m[4] += 1.0f; m[8] += 1.0f;
            float R[9];
            #pragma unroll
            for (int j = 0; j < 9; ++j) R[j] = rotp[(size_t)r * 9 + j];
            float X[9];
            #pragma unroll
            for (int i = 0; i < 3; ++i)
                #pragma unroll
                for (int j = 0; j < 3; ++j)
                    X[i * 3 + j] = R[i * 3 + 0] * m[0 + j]
                                 + R[i * 3 + 1] * m[3 + j]
                                 + R[i * 3 + 2] * m[6 + j];
            // det-scaled Newton polar iteration: X <- 0.5*(mu*X + (1/mu)*cof(X)/det)
            #pragma unroll 1
            for (int it = 0; it < NEWTON_ITERS; ++it) {
                const float c00 = X[4]*X[8] - X[5]*X[7];
                const float c01 = X[5]*X[6] - X[3]*X[8];
                const float c02 = X[3]*X[7] - X[4]*X[6];
                const float c10 = X[2]*X[7] - X[1]*X[8];
                const float c11 = X[0]*X[8] - X[2]*X[6];
                const float c12 = X[1]*X[6] - X[0]*X[7];
                const float c20 = X[1]*X[5] - X[2]*X[4];
                const float c21 = X[2]*X[3] - X[0]*X[5];
                const float c22 = X[0]*X[4] - X[1]*X[3];
                float det = X[0]*c00 + X[1]*c01 + X[2]*c02;
                float ad  = fmaxf(fabsf(det), 1e-30f);
                det = (det < 0.0f) ? -ad : ad;
                const float mu = exp2f(-0.33333333333f * log2f(ad));  // |det|^(-1/3)
                const float ca = 0.5f * mu;
                const float cb = 0.5f / (mu * det);
                float nX[9];
                nX[0] = ca*X[0] + cb*c00; nX[1] = ca*X[1] + cb*c01; nX[2] = ca*X[2] + cb*c02;
                nX[3] = ca*X[3] + cb*c10; nX[4] = ca*X[4] + cb*c11; nX[5] = ca*X[5] + cb*c12;
                nX[6] = ca*X[6] + cb*c20; nX[7] = ca*X[7] + cb*c21; nX[8] = ca*X[8] + cb*c22;
                #pragma unroll
                for (int j = 0; j < 9; ++j) X[j] = nX[j];
            }
            #pragma unroll
            for (int j = 0; j < 9; ++j) out[(size_t)r * 9 + j] = X[j];
            out[(size_t)n * 9 + r] = 0.0f;   // logdet
        }
    }
}

extern "C" void kernel_launch(void* const* d_in, const int* in_sizes, int n_in,
                              void* d_out, int out_size, void* d_ws, size_t ws_size,
                              hipStream_t stream)
{
    const float* rot  = (const float*)d_in[0];
    const float* feat = (const float*)d_in[1];
    const float* W1   = (const float*)d_in[2];
    const float* b1   = (const float*)d_in[3];
    const float* W2   = (const float*)d_in[4];
    const float* b2   = (const float*)d_in[5];
    const float* W3   = (const float*)d_in[6];
    const float* b3   = (const float*)d_in[7];
    float* out = (float*)d_out;
    const int n = in_sizes[0] / 9;
    const int grid = (n + TILE_M - 1) / TILE_M;
    hipLaunchKernelGGL(cond9_fused, dim3(grid), dim3(NTH), 0, stream,
                       rot, feat, W1, b1, W2, b2, W3, b3, out, n);
}

// Round 5
// 1447.204 us; speedup vs baseline: 1.3427x; 1.3427x over previous
//
#include <hip/hip_runtime.h>
#include <math.h>

#define NTH 512
#define BM  64
#define NEWTON_ITERS 18

typedef float f32x4 __attribute__((ext_vector_type(4)));
typedef short s16x8 __attribute__((ext_vector_type(8)));

// ---- fp32 -> 3-term bf16 split (RNE). x ~= b0 + b1 + b2 to ~2^-27 rel. ----
__device__ __forceinline__ ushort bf16rne(float v) {
    unsigned u = __float_as_uint(v);
    return (ushort)((u + 0x7fffu + ((u >> 16) & 1u)) >> 16);
}
__device__ __forceinline__ float bf2f(ushort b) {
    return __uint_as_float(((unsigned)b) << 16);
}
__device__ __forceinline__ void split3(float x, ushort& q0, ushort& q1, ushort& q2) {
    q0 = bf16rne(x); float r = x - bf2f(q0);
    q1 = bf16rne(r); r = r - bf2f(q1);
    q2 = bf16rne(r);
}

// LDS map (bytes):  [0,12288) A-planes   [12288,61440) B-planes   [61440,159744) h1-planes
//  A plane  : [band4][g4][r16][j8] bf16  (256 slots/plane, slot=16B)  x3 planes
//  B plane  : [ct16][g4][c16][j8] bf16   (1024 slots/plane)           x3 planes
//  H planes : [ks8][band4][g4][r16][j8]  (2048 slots/plane)           x3 planes
// Fragment reads are lane-linear 16B slots -> conflict-free ds_read_b128.

__device__ __forceinline__ void stageA(const float* __restrict__ feat, int row0,
                                       int k0, short* sA, int t, int n) {
    const int row = t >> 2, g = t & 3;
    int gr = row0 + row; if (gr >= n) gr = n - 1;
    const float* src = feat + (size_t)gr * 512 + k0 + g * 8;
    const float4 u0 = *reinterpret_cast<const float4*>(src);
    const float4 u1 = *reinterpret_cast<const float4*>(src + 4);
    const float x[8] = {u0.x, u0.y, u0.z, u0.w, u1.x, u1.y, u1.z, u1.w};
    s16x8 v0, v1, v2;
    #pragma unroll
    for (int j = 0; j < 8; ++j) {
        ushort q0, q1, q2; split3(x[j], q0, q1, q2);
        v0[j] = (short)q0; v1[j] = (short)q1; v2[j] = (short)q2;
    }
    const int slot = ((row >> 4) * 4 + g) * 16 + (row & 15);
    *reinterpret_cast<s16x8*>(sA + (size_t)slot * 8)         = v0;
    *reinterpret_cast<s16x8*>(sA + (size_t)(slot + 256) * 8) = v1;
    *reinterpret_cast<s16x8*>(sA + (size_t)(slot + 512) * 8) = v2;
}

__device__ __forceinline__ void stageB(const float* __restrict__ W, int k0,
                                       short* sB, int t) {
    const int u = t - 256;
    const int ct = u >> 4, g = (u >> 2) & 3, c4 = (u & 3) << 2;
    s16x8 v0[4], v1[4], v2[4];
    #pragma unroll
    for (int j = 0; j < 8; ++j) {
        const float4 wv = *reinterpret_cast<const float4*>(
            W + (size_t)(k0 + g * 8 + j) * 256 + ct * 16 + c4);
        const float xv[4] = {wv.x, wv.y, wv.z, wv.w};
        #pragma unroll
        for (int cc = 0; cc < 4; ++cc) {
            ushort q0, q1, q2; split3(xv[cc], q0, q1, q2);
            v0[cc][j] = (short)q0; v1[cc][j] = (short)q1; v2[cc][j] = (short)q2;
        }
    }
    #pragma unroll
    for (int cc = 0; cc < 4; ++cc) {
        const int slot = (ct * 4 + g) * 16 + c4 + cc;
        *reinterpret_cast<s16x8*>(sB + (size_t)slot * 8)          = v0[cc];
        *reinterpret_cast<s16x8*>(sB + (size_t)(slot + 1024) * 8) = v1[cc];
        *reinterpret_cast<s16x8*>(sB + (size_t)(slot + 2048) * 8) = v2[cc];
    }
}

__global__ __launch_bounds__(NTH, 2)
void cond9_mfma(const float* __restrict__ rotp, const float* __restrict__ feat,
                const float* __restrict__ W1, const float* __restrict__ b1,
                const float* __restrict__ W2, const float* __restrict__ b2,
                const float* __restrict__ W3, const float* __restrict__ b3,
                float* __restrict__ out, int n)
{
    __shared__ __align__(16) char smem[159744];
    short* sA = (short*)smem;
    short* sB = (short*)(smem + 12288);
    short* sH = (short*)(smem + 61440);

    const int t    = threadIdx.x;
    const int lane = t & 63;
    const int w    = t >> 6;
    const int wm   = w >> 2, wn = w & 3;       // 2 (M) x 4 (N) wave grid
    const int g    = lane >> 4, rc = lane & 15;
    const int row0 = blockIdx.x * BM;

    f32x4 acc[2][4];
    #pragma unroll
    for (int i = 0; i < 2; ++i)
        #pragma unroll
        for (int jt = 0; jt < 4; ++jt) acc[i][jt] = (f32x4){0.f, 0.f, 0.f, 0.f};

    // =============== GEMM1: h1 = relu(feat @ W1 + b1), K=512 ===============
    for (int ks = 0; ks < 16; ++ks) {
        __syncthreads();
        if (t < 256) stageA(feat, row0, ks * 32, sA, t, n);
        else         stageB(W1, ks * 32, sB, t);
        __syncthreads();
        s16x8 av[2][3], bv[4][3];
        #pragma unroll
        for (int i = 0; i < 2; ++i)
            #pragma unroll
            for (int p = 0; p < 3; ++p)
                av[i][p] = *reinterpret_cast<const s16x8*>(
                    sA + (size_t)(((p * 4 + (wm * 2 + i)) * 4 + g) * 16 + rc) * 8);
        #pragma unroll
        for (int jt = 0; jt < 4; ++jt)
            #pragma unroll
            for (int p = 0; p < 3; ++p)
                bv[jt][p] = *reinterpret_cast<const s16x8*>(
                    sB + (size_t)(((p * 16 + (wn * 4 + jt)) * 4 + g) * 16 + rc) * 8);
        #pragma unroll
        for (int i = 0; i < 2; ++i)
            #pragma unroll
            for (int jt = 0; jt < 4; ++jt) {
                f32x4 c = acc[i][jt];
                c = __builtin_amdgcn_mfma_f32_16x16x32_bf16(av[i][0], bv[jt][0], c, 0, 0, 0);
                c = __builtin_amdgcn_mfma_f32_16x16x32_bf16(av[i][0], bv[jt][1], c, 0, 0, 0);
                c = __builtin_amdgcn_mfma_f32_16x16x32_bf16(av[i][1], bv[jt][0], c, 0, 0, 0);
                c = __builtin_amdgcn_mfma_f32_16x16x32_bf16(av[i][1], bv[jt][1], c, 0, 0, 0);
                c = __builtin_amdgcn_mfma_f32_16x16x32_bf16(av[i][0], bv[jt][2], c, 0, 0, 0);
                c = __builtin_amdgcn_mfma_f32_16x16x32_bf16(av[i][2], bv[jt][0], c, 0, 0, 0);
                acc[i][jt] = c;
            }
    }

    // epilogue 1: bias+relu, split3, write h1 planes in GEMM2 fragment order
    #pragma unroll
    for (int jt = 0; jt < 4; ++jt) {
        const int kcol = wn * 64 + jt * 16 + rc;
        const float bias = b1[kcol];
        const int ks2 = kcol >> 5, g2 = (kcol >> 3) & 3, j2 = kcol & 7;
        #pragma unroll
        for (int i = 0; i < 2; ++i) {
            const int rbase = wm * 32 + i * 16 + g * 4;
            #pragma unroll
            for (int rr = 0; rr < 4; ++rr) {
                const float v = fmaxf(acc[i][jt][rr] + bias, 0.0f);
                ushort q0, q1, q2; split3(v, q0, q1, q2);
                const int row = rbase + rr;
                const int base = (((ks2 * 4 + (row >> 4)) * 4 + g2) * 16 + (row & 15)) * 8 + j2;
                sH[base]          = (short)q0;
                sH[base + 16384]  = (short)q1;
                sH[base + 32768]  = (short)q2;
            }
        }
    }
    #pragma unroll
    for (int i = 0; i < 2; ++i)
        #pragma unroll
        for (int jt = 0; jt < 4; ++jt) acc[i][jt] = (f32x4){0.f, 0.f, 0.f, 0.f};

    // =============== GEMM2: h2 = relu(h1 @ W2 + b2), K=256 ===============
    for (int ks = 0; ks < 8; ++ks) {
        __syncthreads();                 // 1st iter: h1 writes visible, sB free
        if (t >= 256) stageB(W2, ks * 32, sB, t);
        __syncthreads();
        s16x8 av[2][3], bv[4][3];
        #pragma unroll
        for (int i = 0; i < 2; ++i)
            #pragma unroll
            for (int p = 0; p < 3; ++p)
                av[i][p] = *reinterpret_cast<const s16x8*>(
                    sH + (size_t)((((p * 8 + ks) * 4 + (wm * 2 + i)) * 4 + g) * 16 + rc) * 8);
        #pragma unroll
        for (int jt = 0; jt < 4; ++jt)
            #pragma unroll
            for (int p = 0; p < 3; ++p)
                bv[jt][p] = *reinterpret_cast<const s16x8*>(
                    sB + (size_t)(((p * 16 + (wn * 4 + jt)) * 4 + g) * 16 + rc) * 8);
        #pragma unroll
        for (int i = 0; i < 2; ++i)
            #pragma unroll
            for (int jt = 0; jt < 4; ++jt) {
                f32x4 c = acc[i][jt];
                c = __builtin_amdgcn_mfma_f32_16x16x32_bf16(av[i][0], bv[jt][0], c, 0, 0, 0);
                c = __builtin_amdgcn_mfma_f32_16x16x32_bf16(av[i][0], bv[jt][1], c, 0, 0, 0);
                c = __builtin_amdgcn_mfma_f32_16x16x32_bf16(av[i][1], bv[jt][0], c, 0, 0, 0);
                c = __builtin_amdgcn_mfma_f32_16x16x32_bf16(av[i][1], bv[jt][1], c, 0, 0, 0);
                c = __builtin_amdgcn_mfma_f32_16x16x32_bf16(av[i][0], bv[jt][2], c, 0, 0, 0);
                c = __builtin_amdgcn_mfma_f32_16x16x32_bf16(av[i][2], bv[jt][0], c, 0, 0, 0);
                acc[i][jt] = c;
            }
    }

    __syncthreads();   // GEMM2 reads of sH/sB complete before reuse below

    // epilogue 2: h2 fp32 -> sH region as [64][257]; stage W3+b3 into sB region
    float* h2f = (float*)(smem + 61440);
    float* w3f = (float*)(smem + 12288);
    #pragma unroll
    for (int jt = 0; jt < 4; ++jt) {
        const int kcol = wn * 64 + jt * 16 + rc;
        const float bias = b2[kcol];
        #pragma unroll
        for (int i = 0; i < 2; ++i) {
            const int rbase = wm * 32 + i * 16 + g * 4;
            #pragma unroll
            for (int rr = 0; rr < 4; ++rr)
                h2f[(rbase + rr) * 257 + kcol] = fmaxf(acc[i][jt][rr] + bias, 0.0f);
        }
    }
    *reinterpret_cast<float4*>(w3f + t * 4) =
        *reinterpret_cast<const float4*>(W3 + (size_t)t * 4);
    if (t < 64)
        *reinterpret_cast<float4*>(w3f + 2048 + t * 4) =
            *reinterpret_cast<const float4*>(W3 + 2048 + (size_t)t * 4);
    if (t < 9) w3f[2304 + t] = b3[t];
    __syncthreads();

    // =============== GEMM3 (fp32 VALU): out9 = h2 @ W3 + b3 ===============
    float* o9 = (float*)smem;   // sA region reuse
    #pragma unroll
    for (int pass = 0; pass < 2; ++pass) {
        const int tt = t + pass * NTH;
        if (tt < BM * 9) {
            const int row = tt / 9, c = tt - row * 9;
            const float* hrow = h2f + row * 257;
            float s0 = w3f[2304 + c], s1 = 0.f, s2 = 0.f, s3 = 0.f;
            for (int k = 0; k < 256; k += 4) {
                s0 = fmaf(hrow[k + 0], w3f[(k + 0) * 9 + c], s0);
                s1 = fmaf(hrow[k + 1], w3f[(k + 1) * 9 + c], s1);
                s2 = fmaf(hrow[k + 2], w3f[(k + 2) * 9 + c], s2);
                s3 = fmaf(hrow[k + 3], w3f[(k + 3) * 9 + c], s3);
            }
            o9[tt] = (s0 + s1) + (s2 + s3);
        }
    }
    __syncthreads();

    // ===== per-row 3x3: X = rot @ (I + out9); out = polar(X) (= U @ Vh) =====
    if (t < BM) {
        const int r = row0 + t;
        if (r < n) {
            float m[9];
            #pragma unroll
            for (int j = 0; j < 9; ++j) m[j] = o9[t * 9 + j];
            m[0] += 1.0f; m[4] += 1.0f; m[8] += 1.0f;
            float R[9];
            #pragma unroll
            for (int j = 0; j < 9; ++j) R[j] = rotp[(size_t)r * 9 + j];
            float X[9];
            #pragma unroll
            for (int i = 0; i < 3; ++i)
                #pragma unroll
                for (int j = 0; j < 3; ++j)
                    X[i * 3 + j] = R[i * 3 + 0] * m[0 + j]
                                 + R[i * 3 + 1] * m[3 + j]
                                 + R[i * 3 + 2] * m[6 + j];
            #pragma unroll 1
            for (int it = 0; it < NEWTON_ITERS; ++it) {
                const float c00 = X[4]*X[8] - X[5]*X[7];
                const float c01 = X[5]*X[6] - X[3]*X[8];
                const float c02 = X[3]*X[7] - X[4]*X[6];
                const float c10 = X[2]*X[7] - X[1]*X[8];
                const float c11 = X[0]*X[8] - X[2]*X[6];
                const float c12 = X[1]*X[6] - X[0]*X[7];
                const float c20 = X[1]*X[5] - X[2]*X[4];
                const float c21 = X[2]*X[3] - X[0]*X[5];
                const float c22 = X[0]*X[4] - X[1]*X[3];
                float det = X[0]*c00 + X[1]*c01 + X[2]*c02;
                float ad  = fmaxf(fabsf(det), 1e-30f);
                det = (det < 0.0f) ? -ad : ad;
                const float mu = exp2f(-0.33333333333f * log2f(ad));
                const float ca = 0.5f * mu;
                const float cb = 0.5f / (mu * det);
                float nX[9];
                nX[0] = ca*X[0] + cb*c00; nX[1] = ca*X[1] + cb*c01; nX[2] = ca*X[2] + cb*c02;
                nX[3] = ca*X[3] + cb*c10; nX[4] = ca*X[4] + cb*c11; nX[5] = ca*X[5] + cb*c12;
                nX[6] = ca*X[6] + cb*c20; nX[7] = ca*X[7] + cb*c21; nX[8] = ca*X[8] + cb*c22;
                #pragma unroll
                for (int j = 0; j < 9; ++j) X[j] = nX[j];
            }
            #pragma unroll
            for (int j = 0; j < 9; ++j) out[(size_t)r * 9 + j] = X[j];
            out[(size_t)n * 9 + r] = 0.0f;
        }
    }
}

extern "C" void kernel_launch(void* const* d_in, const int* in_sizes, int n_in,
                              void* d_out, int out_size, void* d_ws, size_t ws_size,
                              hipStream_t stream)
{
    const float* rot  = (const float*)d_in[0];
    const float* feat = (const float*)d_in[1];
    const float* W1   = (const float*)d_in[2];
    const float* b1   = (const float*)d_in[3];
    const float* W2   = (const float*)d_in[4];
    const float* b2   = (const float*)d_in[5];
    const float* W3   = (const float*)d_in[6];
    const float* b3   = (const float*)d_in[7];
    float* out = (float*)d_out;
    const int n = in_sizes[0] / 9;
    const int grid = (n + BM - 1) / BM;
    hipLaunchKernelGGL(cond9_mfma, dim3(grid), dim3(NTH), 0, stream,
                       rot, feat, W1, b1, W2, b2, W3, b3, out, n);
}